// Round 1
// 266.352 us; speedup vs baseline: 1.0404x; 1.0404x over previous
//
#include <hip/hip_runtime.h>
#include <cstdint>
#include <cstddef>

// Problem constants: B=4, S=2048, D=1024, H=4096, M = B*S = 8192.
#define MROWS 8192
#define DDIM  1024
#define HDIM  4096

typedef __bf16 bf16x8 __attribute__((ext_vector_type(8)));
typedef float  f32x4  __attribute__((ext_vector_type(4)));

typedef __attribute__((address_space(1))) void* as1_vp;
typedef __attribute__((address_space(3))) void* as3_vp;

__device__ __forceinline__ unsigned short f2bf(float f) {
  unsigned int u = __builtin_bit_cast(unsigned int, f);
  u += 0x7fffu + ((u >> 16) & 1u);   // RNE
  return (unsigned short)(u >> 16);
}
__device__ __forceinline__ float bf2f(unsigned short h) {
  return __builtin_bit_cast(float, (unsigned int)h << 16);
}

// fast gelu: tanh-form, exp2+rcp based. |err vs exact erf-gelu| < ~1e-3.
__device__ __forceinline__ float fast_gelu(float x) {
  float x3 = x * x * x;
  float z = 0.7978845608028654f * x + 0.03567740814f * x3;
  float e = __builtin_amdgcn_exp2f(z * 2.8853900817779268f); // exp(2z)
  float t = 1.0f - 2.0f * __builtin_amdgcn_rcpf(e + 1.0f);   // tanh(z)
  return 0.5f * x * (1.0f + t);
}

__device__ __forceinline__ void gld_lds16(const unsigned short* g, unsigned short* lds) {
  __builtin_amdgcn_global_load_lds((as1_vp)(uintptr_t)g, (as3_vp)lds, 16, 0, 0);
}

// pre_kernel: blocks [0,8192) convert W1,W2 fp32->bf16 (float4 granule);
// blocks [8192,10240) do p1 (wave per row) and emit xb.
// NOTE (R7 lesson): p1/p2 must be produced by BLOCK-LOCAL reductions only —
// cross-block atomic fusion ping-pongs cache lines across XCDs (96->216 us).
__global__ __launch_bounds__(256) void pre_kernel(
    const float* __restrict__ x, const float* __restrict__ w1,
    const float* __restrict__ w2, unsigned short* __restrict__ xb,
    unsigned short* __restrict__ w1b, unsigned short* __restrict__ w2b,
    float* __restrict__ p1) {
  if (blockIdx.x < 8192) {
    int i = blockIdx.x * 256 + threadIdx.x;     // 0..2097151
    const float* src; unsigned short* dst; int off;
    if (i < 1048576) { src = w1; dst = w1b; off = i; }
    else             { src = w2; dst = w2b; off = i - 1048576; }
    float4 v = ((const float4*)src)[off];
    ushort4 o;
    o.x = f2bf(v.x); o.y = f2bf(v.y); o.z = f2bf(v.z); o.w = f2bf(v.w);
    ((ushort4*)dst)[off] = o;
    return;
  }
  const int bid = blockIdx.x - 8192;
  const int wave = threadIdx.x >> 6, lane = threadIdx.x & 63;
  const int m = bid * 4 + wave;
  const int b = m >> 11;
  const float4* xrow4 = (const float4*)(x + (size_t)m * DDIM);
  const float4* od4   = (const float4*)(x + ((size_t)b * 2048 + 2) * DDIM);
  ushort4* xbrow4 = (ushort4*)(xb + (size_t)m * DDIM);
  float a0 = 0.f, a1 = 0.f, a2 = 0.f, a3 = 0.f;
#pragma unroll
  for (int it = 0; it < 4; ++it) {
    int g = it * 64 + lane;
    float4 v = xrow4[g];
    ushort4 o; o.x = f2bf(v.x); o.y = f2bf(v.y); o.z = f2bf(v.z); o.w = f2bf(v.w);
    xbrow4[g] = o;
    float4 o0 = od4[g];
    float4 o1 = od4[512 + g];
    float4 o2 = od4[1024 + g];
    float4 o3 = od4[1536 + g];
    a0 += v.x * o0.x + v.y * o0.y + v.z * o0.z + v.w * o0.w;
    a1 += v.x * o1.x + v.y * o1.y + v.z * o1.z + v.w * o1.w;
    a2 += v.x * o2.x + v.y * o2.y + v.z * o2.z + v.w * o2.w;
    a3 += v.x * o3.x + v.y * o3.y + v.z * o3.z + v.w * o3.w;
  }
#pragma unroll
  for (int off = 32; off > 0; off >>= 1) {
    a0 += __shfl_down(a0, off);
    a1 += __shfl_down(a1, off);
    a2 += __shfl_down(a2, off);
    a3 += __shfl_down(a3, off);
  }
  if (lane == 0) {
    float4 r; r.x = a0; r.y = a1; r.z = a2; r.w = a3;
    ((float4*)p1)[m] = r;
  }
}

// ---------------------------------------------------------------------------
// GEMM1 v2: 256x256 tile, 512 threads (8 waves = 2x4), BK=32, ring-4 LDS
// buffers, deep pipeline with COUNTED vmcnt (T3+T4) + setprio (T5).
//
// Schedule per K-tile t (steady state):
//   STAGE(t+3 -> buf (t+3)&3)      // 4 x global_load_lds, buffer provably free
//   s_waitcnt vmcnt(12)            // forces tile t done; t+1..t+3 stay in flight
//   s_barrier                      // all waves confirmed their slice of tile t
//   ds_read frags; setprio(1); 32 MFMA; setprio(0)
//   s_waitcnt lgkmcnt(0)           // own ds_reads of buf t&3 retired (WAR safety)
//   s_barrier                      // everyone's reads retired -> buf restageable
// Raw asm barriers (NOT __syncthreads) so the compiler never inserts the
// vmcnt(0) full drain — that drain was gemm1 v1's 70% idle (MfmaUtil 30%).
//
// LDS swizzle (BK=32: 4 x 16B slots/row): chunk c of row r stored at slot
// (c + (r>>1)) & 3. Per wave64 ds_read_b128: rows R0+l16, chunk=quad ->
// each bank gets exactly 2 lanes (2-way = free, m136). Stage side writes
// linearly (gld_lds) with the inverse-permuted GLOBAL source address.
// ---------------------------------------------------------------------------
#define VMW(n) asm volatile("s_waitcnt vmcnt(" #n ")" ::: "memory")
#define LKW()  asm volatile("s_waitcnt lgkmcnt(0)" ::: "memory")
#define BAR()  asm volatile("s_barrier" ::: "memory")

__global__ __launch_bounds__(512, 2) void gemm1_kernel(
    const unsigned short* __restrict__ xb, const unsigned short* __restrict__ w1b,
    const float* __restrict__ x, const float* __restrict__ b1,
    const float* __restrict__ p1, const float* __restrict__ scale_p,
    unsigned short* __restrict__ hact) {
  __shared__ __align__(16) unsigned short As[4 * 256 * 32];   // 64 KB
  __shared__ __align__(16) unsigned short Bs[4 * 256 * 32];   // 64 KB

  const int id = blockIdx.x;                 // 512 blocks
  const int xcd = id & 7, w = id >> 3;       // XCD-contiguous m-bands
  const int m0 = (xcd * 4 + (w & 3)) * 256;  // 32 m-tiles
  const int n0 = (w >> 2) * 256;             // 16 n-tiles

  const int tid  = threadIdx.x;
  const int wave = tid >> 6, lane = tid & 63;
  const int quad = lane >> 4, l16 = lane & 15;
  const int wm2  = wave >> 2;                // 0..1 -> 128-row half
  const int wn2  = wave & 3;                 // 0..3 -> 64-col slice

  // Staging addresses. Per load s: 16B-slot index idx = s*512 + tid;
  // r = idx>>2 (row 0..255), sl = idx&3; source chunk c = (sl - (r>>1)) & 3.
  const unsigned short *gA0, *gA1, *gB0, *gB1;
  {
    int idx = tid;
    int r = idx >> 2, sl = idx & 3, c = (sl - (r >> 1)) & 3;
    gA0 = xb  + (size_t)(m0 + r) * DDIM + c * 8;
    gB0 = w1b + (size_t)(n0 + r) * DDIM + c * 8;
    idx = 512 + tid;
    r = idx >> 2; sl = idx & 3; c = (sl - (r >> 1)) & 3;
    gA1 = xb  + (size_t)(m0 + r) * DDIM + c * 8;
    gB1 = w1b + (size_t)(n0 + r) * DDIM + c * 8;
  }
  const int ldsOff0 = (wave * 64) * 8;         // wave-uniform halfword offsets
  const int ldsOff1 = (512 + wave * 64) * 8;

#define STAGE1(tt, sb) do {                                   \
    const int _k = (tt) * 32;                                 \
    unsigned short* _a = &As[(sb) * 8192];                    \
    unsigned short* _b = &Bs[(sb) * 8192];                    \
    gld_lds16(gA0 + _k, _a + ldsOff0);                        \
    gld_lds16(gA1 + _k, _a + ldsOff1);                        \
    gld_lds16(gB0 + _k, _b + ldsOff0);                        \
    gld_lds16(gB1 + _k, _b + ldsOff1);                        \
  } while (0)

  f32x4 acc[8][4];
  const f32x4 z = {0.f, 0.f, 0.f, 0.f};
#pragma unroll
  for (int i = 0; i < 8; ++i)
#pragma unroll
    for (int j = 0; j < 4; ++j) acc[i][j] = z;

  auto compute_tile = [&](const unsigned short* __restrict__ Ab,
                          const unsigned short* __restrict__ Bb) {
    bf16x8 a[8], b[4];
#pragma unroll
    for (int j = 0; j < 4; ++j) {
      const int rb = wn2 * 64 + j * 16 + l16;
      b[j] = *(const bf16x8*)(Bb + rb * 32 + ((quad + (rb >> 1)) & 3) * 8);
    }
#pragma unroll
    for (int i = 0; i < 8; ++i) {
      const int ra = wm2 * 128 + i * 16 + l16;
      a[i] = *(const bf16x8*)(Ab + ra * 32 + ((quad + (ra >> 1)) & 3) * 8);
    }
    __builtin_amdgcn_s_setprio(1);
#pragma unroll
    for (int i = 0; i < 8; ++i)
#pragma unroll
      for (int j = 0; j < 4; ++j)
        acc[i][j] = __builtin_amdgcn_mfma_f32_16x16x32_bf16(a[i], b[j], acc[i][j], 0, 0, 0);
    __builtin_amdgcn_s_setprio(0);
  };

#define TILE_FULL(tt, cb, sb) do {                            \
    STAGE1((tt) + 3, sb);                                     \
    VMW(12);                                                  \
    BAR();                                                    \
    compute_tile(&As[(cb) * 8192], &Bs[(cb) * 8192]);         \
    LKW();                                                    \
    BAR();                                                    \
  } while (0)

  // Prologue: tiles 0,1,2 in flight (12 loads/wave).
  STAGE1(0, 0);
  STAGE1(1, 1);
  STAGE1(2, 2);

#pragma unroll 1
  for (int t = 0; t < 28; t += 4) {     // t multiple of 4 -> buffers constant
    TILE_FULL(t + 0, 0, 3);
    TILE_FULL(t + 1, 1, 0);
    TILE_FULL(t + 2, 2, 1);
    TILE_FULL(t + 3, 3, 2);
  }
  TILE_FULL(28, 0, 3);                  // stages tile 31 (last)
  // Tail: no more staging -> no WAR hazard -> no end barriers needed.
  VMW(8);  BAR(); compute_tile(&As[1 * 8192], &Bs[1 * 8192]);   // t=29
  VMW(4);  BAR(); compute_tile(&As[2 * 8192], &Bs[2 * 8192]);   // t=30
  VMW(0);  BAR(); compute_tile(&As[3 * 8192], &Bs[3 * 8192]);   // t=31

  // Epilogue: gelu( acc + b1 + scale*p1*even ), bf16 store to hact.
  const float sc = scale_p[0];
  const int bidx = m0 >> 11;
  const int i1 = (n0 + wn2 * 64) >> 10;      // wave-uniform lora index
  const float* exrow = x + ((size_t)(bidx * 2048 + 1 + 2 * i1)) * DDIM;

  float exv[4], b1v[4]; int nn[4];
#pragma unroll
  for (int j = 0; j < 4; ++j) {
    nn[j]  = n0 + wn2 * 64 + j * 16 + l16;
    exv[j] = exrow[nn[j] & 1023];
    b1v[j] = b1[nn[j]];
  }
#pragma unroll
  for (int i = 0; i < 8; ++i) {
#pragma unroll
    for (int r = 0; r < 4; ++r) {
      const int m = m0 + wm2 * 128 + i * 16 + quad * 4 + r;
      const float pv = p1[(size_t)m * 4 + i1] * sc;
#pragma unroll
      for (int j = 0; j < 4; ++j) {
        float v = acc[i][j][r] + b1v[j] + pv * exv[j];
        hact[(size_t)m * HDIM + nn[j]] = f2bf(fast_gelu(v));
      }
    }
  }
#undef TILE_FULL
#undef STAGE1
}

// GEMM2 with MFMA-FUSED p2: out = hact.W2^T + b2 + scale*<even2, p2[m,i2,:]>.
// M=8192 N=1024 K=4096, BK=128 (R8). Each block needs only p2[m, i2*4+r] for its
// block-uniform i2 = n0>>8 and its own 128 rows — BLOCK-LOCAL (R7 lesson).
// The dot rides the matrix pipe: b_od fragment = od row (bf16, LDS) in column 0
// only; pacc = mfma(a[i], b_od, pacc) on waves wn==0 (rows covered exactly once).
// Segment r = k0>>10; pacc column 0 flushed to LDS every 8 k0-iters.
// od in bf16 adds ~3e-4 absmax (p2 contribution ~0.08 * 0.4% rel) — negligible.
__global__ __launch_bounds__(256) void gemm2_kernel(
    const unsigned short* __restrict__ hact, const unsigned short* __restrict__ w2b,
    const float* __restrict__ x, const float* __restrict__ b2,
    const float* __restrict__ scale_p, float* __restrict__ out) {
  __shared__ __align__(16) unsigned short As[128 * 128];
  __shared__ __align__(16) unsigned short Bs[128 * 128];
  __shared__ __align__(16) unsigned short od_lds[1024];   // 2 KB
  __shared__ __align__(16) float p2s[128 * 4];            // 2 KB
  const int id = blockIdx.x;
  const int xcd = id & 7, w = id >> 3;
  const int m0 = (xcd * 8 + (w >> 3)) * 128;
  const int n0 = (w & 7) * 128;
  const int tid = threadIdx.x;
  const int wave = tid >> 6, lane = tid & 63, quad = lane >> 4, l16 = lane & 15;
  const int wm = (wave >> 1) * 64, wn = (wave & 1) * 64;
  const int bidx = m0 >> 11;
  const int i2 = n0 >> 8;                    // block-uniform lora index

  // preload od row (odd token 4+i2) as bf16: 1024 floats, 4 per thread
  {
    const float4* src = (const float4*)(x + ((size_t)(bidx * 2048 + 10 + 2 * i2)) * DDIM);
    float4 v = src[tid];
    ushort4 o; o.x = f2bf(v.x); o.y = f2bf(v.y); o.z = f2bf(v.z); o.w = f2bf(v.w);
    ((ushort4*)od_lds)[tid] = o;
  }

  f32x4 acc[4][4];
  const f32x4 z = {0.f, 0.f, 0.f, 0.f};
#pragma unroll
  for (int i = 0; i < 4; ++i)
#pragma unroll
    for (int j = 0; j < 4; ++j) acc[i][j] = z;
  f32x4 pacc[4] = {z, z, z, z};
  const bf16x8 zer8 = __builtin_bit_cast(bf16x8, z);

  const unsigned short* ga[8]; const unsigned short* gb[8];
#pragma unroll
  for (int s = 0; s < 8; ++s) {
    int idx = wave * 512 + s * 64 + lane;   // linear 16B-slot, 2048 per matrix
    int r = idx >> 4, sl = idx & 15;
    int c = (sl - r) & 15;
    ga[s] = hact + (size_t)(m0 + r) * HDIM + c * 8;
    gb[s] = w2b  + (size_t)(n0 + r) * HDIM + c * 8;
  }

  for (int k0 = 0; k0 < HDIM; k0 += 128) {
    __syncthreads();   // also orders the od_lds preload before first use
#pragma unroll
    for (int s = 0; s < 8; ++s) gld_lds16(ga[s] + k0, As + (wave * 8 + s) * 512);
#pragma unroll
    for (int s = 0; s < 8; ++s) gld_lds16(gb[s] + k0, Bs + (wave * 8 + s) * 512);
    __syncthreads();
    const int odbase = k0 & 1023;
#pragma unroll
    for (int kk = 0; kk < 128; kk += 32) {
      bf16x8 a[4], b[4];
      const int cbase = (kk >> 3) + quad;
#pragma unroll
      for (int i = 0; i < 4; ++i) {
        const int ra = wm + i * 16 + l16;
        const int rb = wn + i * 16 + l16;
        a[i] = *(const bf16x8*)(As + ra * 128 + ((cbase + ra) & 15) * 8);
        b[i] = *(const bf16x8*)(Bs + rb * 128 + ((cbase + rb) & 15) * 8);
      }
      if (wn == 0) {   // waves 0,2: rows 0-63 / 64-127 — each row exactly once
        bf16x8 odv = *(const bf16x8*)(od_lds + odbase + kk + quad * 8);  // broadcast read
        bf16x8 bod = (l16 == 0) ? odv : zer8;   // od in column 0 only
#pragma unroll
        for (int i = 0; i < 4; ++i)
          pacc[i] = __builtin_amdgcn_mfma_f32_16x16x32_bf16(a[i], bod, pacc[i], 0, 0, 0);
      }
#pragma unroll
      for (int i = 0; i < 4; ++i)
#pragma unroll
        for (int j = 0; j < 4; ++j)
          acc[i][j] = __builtin_amdgcn_mfma_f32_16x16x32_bf16(a[i], b[j], acc[i][j], 0, 0, 0);
    }
    if (((k0 + 128) & 1023) == 0) {          // segment boundary: flush column 0
      const int seg = k0 >> 10;
      if (wn == 0) {
        if (l16 == 0) {
#pragma unroll
          for (int i = 0; i < 4; ++i)
#pragma unroll
            for (int e = 0; e < 4; ++e)
              p2s[(wm + i * 16 + quad * 4 + e) * 4 + seg] = pacc[i][e];
        }
#pragma unroll
        for (int i = 0; i < 4; ++i) pacc[i] = z;
      }
    }
  }
  __syncthreads();                           // p2s visible to all waves

  const float sc = scale_p[0];
  const float* evrow = x + ((size_t)(bidx * 2048 + 9 + 2 * i2)) * DDIM;

  float4 ev[4]; float b2v[4]; int nn[4];
#pragma unroll
  for (int j = 0; j < 4; ++j) {
    nn[j] = n0 + wn + j * 16 + l16;
    ev[j]  = *(const float4*)(evrow + 4 * (nn[j] & 255));
    b2v[j] = b2[nn[j]];
  }
#pragma unroll
  for (int i = 0; i < 4; ++i) {
#pragma unroll
    for (int r = 0; r < 4; ++r) {
      const int mloc = wm + i * 16 + quad * 4 + r;
      const int m = m0 + mloc;
      const float4 pv = *(const float4*)(p2s + mloc * 4);  // broadcast across l16
#pragma unroll
      for (int j = 0; j < 4; ++j) {
        float lora = ev[j].x * pv.x + ev[j].y * pv.y + ev[j].z * pv.z + ev[j].w * pv.w;
        out[(size_t)m * DDIM + nn[j]] = acc[i][j][r] + b2v[j] + sc * lora;
      }
    }
  }
}

extern "C" void kernel_launch(void* const* d_in, const int* in_sizes, int n_in,
                              void* d_out, int out_size, void* d_ws, size_t ws_size,
                              hipStream_t stream) {
  const float* x     = (const float*)d_in[0];
  const float* W1    = (const float*)d_in[1];
  const float* b1    = (const float*)d_in[2];
  const float* W2    = (const float*)d_in[3];
  const float* b2    = (const float*)d_in[4];
  const float* scale = (const float*)d_in[5];
  float* out = (float*)d_out;

  char* ws = (char*)d_ws;
  unsigned short* xb   = (unsigned short*)(ws);                // 16 MiB
  unsigned short* w1b  = (unsigned short*)(ws + 16777216);     //  8 MiB
  unsigned short* w2b  = (unsigned short*)(ws + 25165824);     //  8 MiB
  unsigned short* hact = (unsigned short*)(ws + 33554432);     // 64 MiB
  float*          p1   = (float*)(ws + 100663296);             // 128 KiB

  pre_kernel<<<dim3(10240), dim3(256), 0, stream>>>(x, W1, W2, xb, w1b, w2b, p1);
  gemm1_kernel<<<dim3(512), dim3(512), 0, stream>>>(xb, w1b, x, b1, p1, scale, hact);
  gemm2_kernel<<<dim3(512), dim3(256), 0, stream>>>(hact, w2b, x, b2, scale, out);
}